// Round 10
// baseline (673.306 us; speedup 1.0000x reference)
//
#include <hip/hip_runtime.h>
#include <hip/hip_fp16.h>
#include <math.h>

#define N_NODES 100000
#define N_EDGES 3200000
#define F_IN    384
#define H1      128
#define H2      64

#define NBKT    782          // ceil(N_NODES / 128)
#define HIST_W  800          // padded bucket-row width
#define NB_BIN  256          // binning blocks
#define EPB     (N_EDGES / NB_BIN)   // 12500 edges per bin block

typedef _Float16 f16x8 __attribute__((ext_vector_type(8)));
typedef float    f32x4 __attribute__((ext_vector_type(4)));

// ---------------- phase A1: per-block bucket histograms ----------------

__global__ __launch_bounds__(256) void k_hist(const int* __restrict__ dst,
                                              int* __restrict__ hist) {
    __shared__ int h[HIST_W];
    int b = blockIdx.x, t = threadIdx.x;
    for (int i = t; i < HIST_W; i += 256) h[i] = 0;
    __syncthreads();
    int e0 = b * EPB, e1 = e0 + EPB;
    for (int e = e0 + t; e < e1; e += 256)
        atomicAdd(&h[dst[e] >> 7], 1);
    __syncthreads();
    for (int i = t; i < HIST_W; i += 256) hist[b * HIST_W + i] = h[i];
}

// ---------------- phase A2: bucket bases + per-(block,bucket) offsets ----------------

__global__ __launch_bounds__(1024) void k_scan_off(int* __restrict__ hist,
                                                   int* __restrict__ bucketBase) {
    __shared__ int s[1024];
    int t = threadIdx.x;
    int run = 0;
    if (t < HIST_W) {
        #pragma unroll 8
        for (int b = 0; b < NB_BIN; b++) {
            int v = hist[b * HIST_W + t];
            hist[b * HIST_W + t] = run;   // prefix over blocks, within bucket
            run += v;
        }
    }
    int tot = (t < NBKT) ? run : 0;
    s[t] = tot; __syncthreads();
    for (int off = 1; off < 1024; off <<= 1) {
        int x = (t >= off) ? s[t - off] : 0;
        __syncthreads();
        s[t] += x;
        __syncthreads();
    }
    if (t <= NBKT) bucketBase[t] = s[t] - tot;   // exclusive over buckets
}

// ---------------- phase A3: scatter packed edges into bucket order ----------------

__global__ __launch_bounds__(256) void k_bin(const int* __restrict__ src,
                                             const int* __restrict__ dst,
                                             const int* __restrict__ hist,
                                             const int* __restrict__ bucketBase,
                                             int* __restrict__ binned) {
    __shared__ int lcur[HIST_W];
    int b = blockIdx.x, t = threadIdx.x;
    for (int i = t; i < HIST_W; i += 256)
        lcur[i] = ((i < NBKT) ? bucketBase[i] : 0) + hist[b * HIST_W + i];
    __syncthreads();
    int e0 = b * EPB, e1 = e0 + EPB;
    for (int e = e0 + t; e < e1; e += 256) {
        int d = dst[e];
        int p = atomicAdd(&lcur[d >> 7], 1);
        binned[p] = ((d & 127) << 17) | src[e];   // src < 2^17
    }
}

// ---------------- phase B: per-bucket deg/dis/offsets/csr (all in LDS) ----------------

__global__ __launch_bounds__(256) void k_build(const int* __restrict__ binned,
                                               const int* __restrict__ bucketBase,
                                               int* __restrict__ csr,
                                               int* __restrict__ offsets,
                                               int* __restrict__ ecnt,
                                               float* __restrict__ dis) {
    __shared__ int ldeg[128], spre[128], lcur[128];
    int bkt = blockIdx.x, t = threadIdx.x;
    int e0 = bucketBase[bkt], e1 = bucketBase[bkt + 1];
    if (t < 128) ldeg[t] = 0;
    __syncthreads();
    for (int e = e0 + t; e < e1; e += 256)
        atomicAdd(&ldeg[binned[e] >> 17], 1);
    __syncthreads();
    int v = (t < 128) ? ldeg[t] : 0;
    if (t < 128) spre[t] = v;
    __syncthreads();
    for (int off = 1; off < 128; off <<= 1) {
        int x = (t < 128 && t >= off) ? spre[t - off] : 0;
        __syncthreads();
        if (t < 128) spre[t] += x;
        __syncthreads();
    }
    if (t < 128) {
        int node = bkt * 128 + t;
        if (node < N_NODES) {
            int base = e0 + spre[t] - v;   // exclusive prefix within bucket
            offsets[node] = base;
            ecnt[node]    = v;             // neighbors excluding self-loop
            dis[node]     = rsqrtf((float)(v + 1));
            lcur[t]       = base;
        }
    }
    __syncthreads();
    for (int e = e0 + t; e < e1; e += 256) {
        int p = binned[e];
        int pos = atomicAdd(&lcur[p >> 17], 1);
        csr[pos] = p & 0x1FFFF;
    }
}

// ---------------- weight transposes to fp16 ----------------

__global__ __launch_bounds__(256) void k_w1t(const float* __restrict__ W1,
                                             __half* __restrict__ w1t) {
    int id = blockIdx.x * 256 + threadIdx.x;   // over H1*F_IN
    int c = id / F_IN, k = id % F_IN;
    w1t[id] = __float2half_rn(W1[(size_t)k * H1 + c]);
}

__global__ __launch_bounds__(256) void k_w2t(const float* __restrict__ W2,
                                             __half* __restrict__ w2t) {
    int id = blockIdx.x * 256 + threadIdx.x;   // over H2*H1
    int c = id / H1, k = id % H1;
    w2t[id] = __float2half_rn(W2[(size_t)k * H2 + c]);
}

// ---------------- GEMM1 (MFMA): hs1[slab][row][0..15] = fp16(dis * (x @ W1)) ----------------
// 64x128 tile, BK=64, 4 waves x (16 rows x 128 cols) each. Output slabbed by 16-col blocks.

__global__ __launch_bounds__(256) void k_gemm1(const float* __restrict__ x,
                                               const __half* __restrict__ w1t,
                                               const float* __restrict__ dis,
                                               __half* __restrict__ hs1) {
    __shared__ f16x8 xl[512];    // 64 rows x 64 k fp16, XOR-swizzled 16B slots
    __shared__ f16x8 wt[1024];   // 128 cols x 64 k fp16, XOR-swizzled
    int t = threadIdx.x;
    int m0 = blockIdx.x * 64;
    int wv = t >> 6, l = t & 63;
    int lrow = l & 15, kg = l >> 4;
    f32x4 acc[8];
    #pragma unroll
    for (int nb = 0; nb < 8; nb++) acc[nb] = (f32x4){0.f, 0.f, 0.f, 0.f};

    char* xb = (char*)xl;
    char* wb = (char*)wt;

    for (int k0 = 0; k0 < F_IN; k0 += 64) {
        #pragma unroll
        for (int j = 0; j < 2; j++) {            // stage x tile (fp32 -> fp16)
            int s = t + j * 256;
            int r = s >> 3, kc = (s & 7) * 8;
            int rg = m0 + r; if (rg >= N_NODES) rg = N_NODES - 1;
            const float* px = &x[(size_t)rg * F_IN + k0 + kc];
            float4 p0 = *(const float4*)px;
            float4 p1 = *(const float4*)(px + 4);
            f16x8 h;
            h[0] = (_Float16)p0.x; h[1] = (_Float16)p0.y;
            h[2] = (_Float16)p0.z; h[3] = (_Float16)p0.w;
            h[4] = (_Float16)p1.x; h[5] = (_Float16)p1.y;
            h[6] = (_Float16)p1.z; h[7] = (_Float16)p1.w;
            *(f16x8*)(xb + ((r * 128 + kc * 2) ^ ((r & 7) << 4))) = h;
        }
        #pragma unroll
        for (int j = 0; j < 4; j++) {            // stage W1^T slab (already fp16)
            int s = t + j * 256;
            int c = s >> 3, kc = (s & 7) * 8;
            f16x8 h = *(const f16x8*)&w1t[(size_t)c * F_IN + k0 + kc];
            *(f16x8*)(wb + ((c * 128 + kc * 2) ^ ((c & 7) << 4))) = h;
        }
        __syncthreads();
        #pragma unroll
        for (int ks = 0; ks < 2; ks++) {
            int r = wv * 16 + lrow;
            int kb = (ks * 32 + kg * 8) * 2;
            f16x8 a = *(const f16x8*)(xb + ((r * 128 + kb) ^ ((r & 7) << 4)));
            #pragma unroll
            for (int nb = 0; nb < 8; nb++) {
                int c = nb * 16 + lrow;
                f16x8 b = *(const f16x8*)(wb + ((c * 128 + kb) ^ ((c & 7) << 4)));
                acc[nb] = __builtin_amdgcn_mfma_f32_16x16x32_f16(a, b, acc[nb], 0, 0, 0);
            }
        }
        __syncthreads();
    }
    // D layout: col = lane&15, row = (lane>>4)*4 + reg ; slab = nb
    int rbase = m0 + wv * 16 + kg * 4;
    #pragma unroll
    for (int reg = 0; reg < 4; reg++) {
        int row = rbase + reg;
        if (row < N_NODES) {
            float dr = dis[row];
            #pragma unroll
            for (int nb = 0; nb < 8; nb++)
                hs1[(((size_t)nb * N_NODES + row) << 4) + lrow] =
                    __float2half_rn(acc[nb][reg] * dr);
        }
    }
}

// ---------------- agg1: hr16 = fp16(relu(di * (sum hs1[s] + hs1[w]) + b1)) ----------------
// Slabbed: slab = blockIdx.x & 7 (XCD-pinned, 3.2 MB slab resident in per-XCD L2).
// 4 lanes per node x 16 nodes per wave.

__global__ __launch_bounds__(256) void k_agg1(const __half* __restrict__ hs1,
                                              const float* __restrict__ dis,
                                              const int* __restrict__ csr,
                                              const int* __restrict__ offsets,
                                              const int* __restrict__ ecnt,
                                              const float* __restrict__ b1,
                                              __half* __restrict__ hr16) {
    int t = threadIdx.x;
    int slab = blockIdx.x & 7;
    int w = (blockIdx.x >> 3) * 64 + (t >> 2);
    if (w >= N_NODES) return;
    int f4 = (t & 3) << 2;
    const __half* __restrict__ hp = hs1 + (((size_t)slab * N_NODES) << 4);
    float di = dis[w];
    int start = offsets[w];
    int cnt = ecnt[w];
    uint2 r0 = *(const uint2*)(hp + (((unsigned)w) << 4) + f4);
    float2 s0 = __half22float2(*(__half2*)&r0.x);
    float2 s1 = __half22float2(*(__half2*)&r0.y);
    float a0 = s0.x, a1 = s0.y, a2 = s1.x, a3 = s1.y;

    int kf = cnt & ~7;
    for (int k = 0; k < kf; k += 8) {
        int s[8]; uint2 r[8];
        #pragma unroll
        for (int u = 0; u < 8; u++) s[u] = csr[start + k + u];
        #pragma unroll
        for (int u = 0; u < 8; u++)
            r[u] = *(const uint2*)(hp + (((unsigned)s[u]) << 4) + f4);
        #pragma unroll
        for (int u = 0; u < 8; u++) {
            float2 f0 = __half22float2(*(__half2*)&r[u].x);
            float2 f1 = __half22float2(*(__half2*)&r[u].y);
            a0 += f0.x; a1 += f0.y; a2 += f1.x; a3 += f1.y;
        }
    }
    for (int k = kf; k < cnt; k++) {
        int s = csr[start + k];
        uint2 rr = *(const uint2*)(hp + (((unsigned)s) << 4) + f4);
        float2 f0 = __half22float2(*(__half2*)&rr.x);
        float2 f1 = __half22float2(*(__half2*)&rr.y);
        a0 += f0.x; a1 += f0.y; a2 += f1.x; a3 += f1.y;
    }
    int fc = slab * 16 + f4;
    float4 bb = *(const float4*)&b1[fc];
    __half2 o0 = __floats2half2_rn(fmaxf(bb.x + di * a0, 0.f), fmaxf(bb.y + di * a1, 0.f));
    __half2 o1 = __floats2half2_rn(fmaxf(bb.z + di * a2, 0.f), fmaxf(bb.w + di * a3, 0.f));
    uint2 ov; *(__half2*)&ov.x = o0; *(__half2*)&ov.y = o1;
    *(uint2*)(hr16 + (((size_t)w) << 7) + fc) = ov;
}

// ---------------- GEMM2 (MFMA): hs2[slab][row][0..15] = fp16(dis * (hr @ W2)) ----------------
// 64x64 tile, BK=128 (whole H1), 4 waves x (16 rows x 64 cols). hr already fp16.

__global__ __launch_bounds__(256) void k_gemm2(const __half* __restrict__ hr16,
                                               const __half* __restrict__ w2t,
                                               const float* __restrict__ dis,
                                               __half* __restrict__ hs2) {
    __shared__ f16x8 al[1024];   // 64 rows x 128 k fp16, XOR-swizzled
    __shared__ f16x8 bl[1024];   // 64 cols x 128 k fp16, XOR-swizzled
    int t = threadIdx.x;
    int m0 = blockIdx.x * 64;
    int wv = t >> 6, l = t & 63;
    int lrow = l & 15, kg = l >> 4;
    char* ab = (char*)al;
    char* bb = (char*)bl;

    #pragma unroll
    for (int j = 0; j < 4; j++) {            // stage hr tile (fp16 direct)
        int s = t + j * 256;
        int r = s >> 4, kc = (s & 15) * 8;
        int rg = m0 + r; if (rg >= N_NODES) rg = N_NODES - 1;
        f16x8 h = *(const f16x8*)&hr16[(size_t)rg * H1 + kc];
        *(f16x8*)(ab + ((r * 256 + kc * 2) ^ ((r & 7) << 4))) = h;
    }
    #pragma unroll
    for (int j = 0; j < 4; j++) {            // stage W2^T (fp16)
        int s = t + j * 256;
        int c = s >> 4, kc = (s & 15) * 8;
        f16x8 h = *(const f16x8*)&w2t[(size_t)c * H1 + kc];
        *(f16x8*)(bb + ((c * 256 + kc * 2) ^ ((c & 7) << 4))) = h;
    }
    __syncthreads();

    f32x4 acc[4];
    #pragma unroll
    for (int nb = 0; nb < 4; nb++) acc[nb] = (f32x4){0.f, 0.f, 0.f, 0.f};
    #pragma unroll
    for (int ks = 0; ks < 4; ks++) {
        int r = wv * 16 + lrow;
        int kb = (ks * 32 + kg * 8) * 2;
        f16x8 a = *(const f16x8*)(ab + ((r * 256 + kb) ^ ((r & 7) << 4)));
        #pragma unroll
        for (int nb = 0; nb < 4; nb++) {
            int c = nb * 16 + lrow;
            f16x8 b = *(const f16x8*)(bb + ((c * 256 + kb) ^ ((c & 7) << 4)));
            acc[nb] = __builtin_amdgcn_mfma_f32_16x16x32_f16(a, b, acc[nb], 0, 0, 0);
        }
    }
    int rbase = m0 + wv * 16 + kg * 4;
    #pragma unroll
    for (int reg = 0; reg < 4; reg++) {
        int row = rbase + reg;
        if (row < N_NODES) {
            float dr = dis[row];
            #pragma unroll
            for (int nb = 0; nb < 4; nb++)
                hs2[(((size_t)nb * N_NODES + row) << 4) + lrow] =
                    __float2half_rn(acc[nb][reg] * dr);
        }
    }
}

// ---------------- agg2: out = b2 + di * (sum hs2[s] + hs2[w]) ----------------
// 4 slabs over 8 XCDs: each XCD-pair shares a slab, splitting nodes.

__global__ __launch_bounds__(256) void k_agg2(const __half* __restrict__ hs2,
                                              const float* __restrict__ dis,
                                              const int* __restrict__ csr,
                                              const int* __restrict__ offsets,
                                              const int* __restrict__ ecnt,
                                              const float* __restrict__ b2,
                                              float* __restrict__ out) {
    int t = threadIdx.x;
    int xcd = blockIdx.x & 7;
    int slab = xcd >> 1;
    int chunk = (blockIdx.x >> 3) * 2 + (xcd & 1);
    int w = chunk * 64 + (t >> 2);
    if (w >= N_NODES) return;
    int f4 = (t & 3) << 2;
    const __half* __restrict__ hp = hs2 + (((size_t)slab * N_NODES) << 4);
    float di = dis[w];
    int start = offsets[w];
    int cnt = ecnt[w];
    uint2 r0 = *(const uint2*)(hp + (((unsigned)w) << 4) + f4);
    float2 s0 = __half22float2(*(__half2*)&r0.x);
    float2 s1 = __half22float2(*(__half2*)&r0.y);
    float a0 = s0.x, a1 = s0.y, a2 = s1.x, a3 = s1.y;

    int kf = cnt & ~7;
    for (int k = 0; k < kf; k += 8) {
        int s[8]; uint2 r[8];
        #pragma unroll
        for (int u = 0; u < 8; u++) s[u] = csr[start + k + u];
        #pragma unroll
        for (int u = 0; u < 8; u++)
            r[u] = *(const uint2*)(hp + (((unsigned)s[u]) << 4) + f4);
        #pragma unroll
        for (int u = 0; u < 8; u++) {
            float2 f0 = __half22float2(*(__half2*)&r[u].x);
            float2 f1 = __half22float2(*(__half2*)&r[u].y);
            a0 += f0.x; a1 += f0.y; a2 += f1.x; a3 += f1.y;
        }
    }
    for (int k = kf; k < cnt; k++) {
        int s = csr[start + k];
        uint2 rr = *(const uint2*)(hp + (((unsigned)s) << 4) + f4);
        float2 f0 = __half22float2(*(__half2*)&rr.x);
        float2 f1 = __half22float2(*(__half2*)&rr.y);
        a0 += f0.x; a1 += f0.y; a2 += f1.x; a3 += f1.y;
    }
    int fc = slab * 16 + f4;
    float4 bb = *(const float4*)&b2[fc];
    float4 o = make_float4(bb.x + di * a0, bb.y + di * a1,
                           bb.z + di * a2, bb.w + di * a3);
    *(float4*)&out[(((size_t)w) << 6) + fc] = o;
}

// ---------------- launch ----------------

extern "C" void kernel_launch(void* const* d_in, const int* in_sizes, int n_in,
                              void* d_out, int out_size, void* d_ws, size_t ws_size,
                              hipStream_t stream) {
    const float* x  = (const float*)d_in[0];
    const float* W1 = (const float*)d_in[1];
    const float* b1 = (const float*)d_in[2];
    const float* W2 = (const float*)d_in[3];
    const float* b2 = (const float*)d_in[4];
    const int*   ei = (const int*)d_in[5];
    const int* src = ei;
    const int* dst = ei + N_EDGES;
    float* out = (float*)d_out;

    char* ws = (char*)d_ws;
    float* dis        = (float*)ws; ws += (size_t)N_NODES * 4;
    int*   offsets    = (int*)ws;   ws += (size_t)N_NODES * 4;
    int*   ecnt       = (int*)ws;   ws += (size_t)N_NODES * 4;
    int*   bucketBase = (int*)ws;   ws += 1024 * 4;
    int*   hist       = (int*)ws;   ws += (size_t)NB_BIN * HIST_W * 4;
    int*   csr        = (int*)ws;   ws += (size_t)N_EDGES * 4;
    __half* w1t       = (__half*)ws; ws += (size_t)H1 * F_IN * 2;
    __half* w2t       = (__half*)ws; ws += (size_t)H2 * H1 * 2;
    __half* hs1       = (__half*)ws; ws += (size_t)N_NODES * H1 * 2;
    __half* hr16      = (__half*)ws; ws += (size_t)N_NODES * H1 * 2;
    int*   binned     = (int*)hr16; // dead before agg1 writes hr16
    __half* hs2       = hs1;        // hs1 dead after agg1

    k_w1t     <<<(H1 * F_IN) / 256, 256, 0, stream>>>(W1, w1t);
    k_w2t     <<<(H2 * H1) / 256, 256, 0, stream>>>(W2, w2t);
    k_hist    <<<NB_BIN, 256, 0, stream>>>(dst, hist);
    k_scan_off<<<1, 1024, 0, stream>>>(hist, bucketBase);
    k_bin     <<<NB_BIN, 256, 0, stream>>>(src, dst, hist, bucketBase, binned);
    k_build   <<<NBKT, 256, 0, stream>>>(binned, bucketBase, csr, offsets, ecnt, dis);

    k_gemm1<<<(N_NODES + 63) / 64, 256, 0, stream>>>(x, w1t, dis, hs1);
    k_agg1<<<((N_NODES + 63) / 64) * 8, 256, 0, stream>>>(hs1, dis, csr, offsets, ecnt, b1, hr16);
    k_gemm2<<<(N_NODES + 63) / 64, 256, 0, stream>>>(hr16, w2t, dis, hs2);
    k_agg2<<<((N_NODES + 127) / 128) * 8, 256, 0, stream>>>(hs2, dis, csr, offsets, ecnt, b2, out);
}